// Round 1
// baseline (6775.053 us; speedup 1.0000x reference)
//
#include <hip/hip_runtime.h>

#define D_MODEL 1024
#define NUM_HEADS 16
#define D_K 64
#define BATCH 2
#define SEQ 2048
#define TQ 8

// ---------------------------------------------------------------------------
// Tiled fp32 GEMM: C[M,1024] = A[M,1024] @ W[1024,1024] + bias[1024]
// 64x64 tile per 256-thread block, 4x4 micro-tile per thread, K-tile = 16.
// (unchanged from previous round)
// ---------------------------------------------------------------------------
__global__ __launch_bounds__(256)
void gemm_bias_kernel(const float* __restrict__ A, const float* __restrict__ W,
                      const float* __restrict__ bias, float* __restrict__ C) {
    __shared__ float As[16][64];   // [k][row] (transposed for broadcast reads)
    __shared__ float Bs[16][64];   // [k][col]

    const int tid = threadIdx.x;
    const int tx = tid & 15;        // 0..15 -> col group
    const int ty = tid >> 4;        // 0..15 -> row group
    const int rowBase = blockIdx.y * 64;
    const int colBase = blockIdx.x * 64;

    const int ar = tid >> 2;            // 0..63  A-tile row
    const int ac = (tid & 3) * 4;       // 0,4,8,12 A-tile k-offset
    const int br = tid >> 4;            // 0..15  W-tile k-row
    const int bc = (tid & 15) * 4;      // 0..60  W-tile col

    float acc[4][4] = {};

    for (int k0 = 0; k0 < D_MODEL; k0 += 16) {
        float4 av = *(const float4*)(A + (size_t)(rowBase + ar) * D_MODEL + k0 + ac);
        float4 bv = *(const float4*)(W + (size_t)(k0 + br) * D_MODEL + colBase + bc);
        __syncthreads();   // previous iteration's LDS reads must finish
        As[ac + 0][ar] = av.x;
        As[ac + 1][ar] = av.y;
        As[ac + 2][ar] = av.z;
        As[ac + 3][ar] = av.w;
        *(float4*)&Bs[br][bc] = bv;
        __syncthreads();
#pragma unroll
        for (int kk = 0; kk < 16; ++kk) {
            const float a0 = As[kk][ty * 4 + 0];
            const float a1 = As[kk][ty * 4 + 1];
            const float a2 = As[kk][ty * 4 + 2];
            const float a3 = As[kk][ty * 4 + 3];
            const float4 b = *(const float4*)&Bs[kk][tx * 4];
            acc[0][0] += a0 * b.x; acc[0][1] += a0 * b.y; acc[0][2] += a0 * b.z; acc[0][3] += a0 * b.w;
            acc[1][0] += a1 * b.x; acc[1][1] += a1 * b.y; acc[1][2] += a1 * b.z; acc[1][3] += a1 * b.w;
            acc[2][0] += a2 * b.x; acc[2][1] += a2 * b.y; acc[2][2] += a2 * b.z; acc[2][3] += a2 * b.w;
            acc[3][0] += a3 * b.x; acc[3][1] += a3 * b.y; acc[3][2] += a3 * b.z; acc[3][3] += a3 * b.w;
        }
    }

    const float4 bb = *(const float4*)(bias + colBase + tx * 4);
#pragma unroll
    for (int i = 0; i < 4; ++i) {
        float4 o;
        o.x = acc[i][0] + bb.x;
        o.y = acc[i][1] + bb.y;
        o.z = acc[i][2] + bb.z;
        o.w = acc[i][3] + bb.w;
        *(float4*)(C + (size_t)(rowBase + ty * 4 + i) * D_MODEL + colBase + tx * 4) = o;
    }
}

// ---------------------------------------------------------------------------
// Attention: one block per (b, h, 8 query rows). 512 threads (8 waves).
// Register-micro-tiled scores (8q x 4k per thread) and PV (8q x 4d per thread),
// all LDS traffic vectorized b128 or broadcast; wave-shuffle softmax reductions.
// ---------------------------------------------------------------------------
__global__ __launch_bounds__(512)
void attn_kernel(const float* __restrict__ Qp, const float* __restrict__ Kp,
                 const float* __restrict__ Vp, float* __restrict__ attn,
                 float* __restrict__ ctx) {
    const int b  = blockIdx.z;
    const int h  = blockIdx.y;
    const int q0 = blockIdx.x * TQ;
    const int tid  = threadIdx.x;
    const int lane = tid & 63;
    const int wid  = tid >> 6;

    __shared__ float qv[TQ][64];        // 2 KB
    __shared__ float sc[TQ][SEQ];       // 64 KB un-normalized exp; reused as PV-reduce buffer
    __shared__ float wredm[TQ][8];      // per-wave max partials
    __shared__ float wreds[TQ][8];      // per-wave sum partials

    // ---- load 8 query vectors (512 threads = 8*64 elements) ----
    {
        const int q = tid >> 6, d = tid & 63;
        qv[q][d] = Qp[((size_t)(b * SEQ + q0 + q)) * D_MODEL + h * 64 + d];
    }
    __syncthreads();

    // ---- scores: each thread computes 4 k-columns (tid + 512*i) for all 8 rows ----
    float loc[TQ][4];
#pragma unroll
    for (int q = 0; q < TQ; ++q)
#pragma unroll
        for (int i = 0; i < 4; ++i) loc[q][i] = 0.f;

    const float* Kb = Kp + ((size_t)b * SEQ) * D_MODEL + h * 64;
#pragma unroll
    for (int dc = 0; dc < 64; dc += 16) {
        // broadcast Q fragment for this d-chunk into registers (conflict-free)
        float4 qreg[TQ][4];
#pragma unroll
        for (int q = 0; q < TQ; ++q)
#pragma unroll
            for (int j = 0; j < 4; ++j)
                qreg[q][j] = *(const float4*)&qv[q][dc + 4 * j];
#pragma unroll
        for (int i = 0; i < 4; ++i) {
            const float* Kr = Kb + (size_t)(tid + i * 512) * D_MODEL + dc;
            const float4 kv0 = *(const float4*)(Kr + 0);
            const float4 kv1 = *(const float4*)(Kr + 4);
            const float4 kv2 = *(const float4*)(Kr + 8);
            const float4 kv3 = *(const float4*)(Kr + 12);
#pragma unroll
            for (int q = 0; q < TQ; ++q) {
                loc[q][i] += qreg[q][0].x * kv0.x + qreg[q][0].y * kv0.y +
                             qreg[q][0].z * kv0.z + qreg[q][0].w * kv0.w +
                             qreg[q][1].x * kv1.x + qreg[q][1].y * kv1.y +
                             qreg[q][1].z * kv1.z + qreg[q][1].w * kv1.w +
                             qreg[q][2].x * kv2.x + qreg[q][2].y * kv2.y +
                             qreg[q][2].z * kv2.z + qreg[q][2].w * kv2.w +
                             qreg[q][3].x * kv3.x + qreg[q][3].y * kv3.y +
                             qreg[q][3].z * kv3.z + qreg[q][3].w * kv3.w;
            }
        }
    }
    const float scale = 0.125f;   // 1/sqrt(64)
#pragma unroll
    for (int q = 0; q < TQ; ++q)
#pragma unroll
        for (int i = 0; i < 4; ++i) loc[q][i] *= scale;

    // ---- row max: thread-local -> wave shuffle -> cross-wave via LDS ----
    float m[TQ];
#pragma unroll
    for (int q = 0; q < TQ; ++q) {
        float lm = fmaxf(fmaxf(loc[q][0], loc[q][1]), fmaxf(loc[q][2], loc[q][3]));
#pragma unroll
        for (int st = 32; st > 0; st >>= 1) lm = fmaxf(lm, __shfl_xor(lm, st, 64));
        if (lane == 0) wredm[q][wid] = lm;
    }
    __syncthreads();
#pragma unroll
    for (int q = 0; q < TQ; ++q) {
        float mm = wredm[q][0];
#pragma unroll
        for (int w = 1; w < 8; ++w) mm = fmaxf(mm, wredm[q][w]);
        m[q] = mm;
    }

    // ---- exp, stash un-normalized in LDS, row-sum ----
#pragma unroll
    for (int q = 0; q < TQ; ++q) {
        float ls = 0.f;
#pragma unroll
        for (int i = 0; i < 4; ++i) {
            const float e = __expf(loc[q][i] - m[q]);
            loc[q][i] = e;
            sc[q][tid + i * 512] = e;
            ls += e;
        }
#pragma unroll
        for (int st = 32; st > 0; st >>= 1) ls += __shfl_xor(ls, st, 64);
        if (lane == 0) wreds[q][wid] = ls;
    }
    __syncthreads();
    float inv[TQ];
#pragma unroll
    for (int q = 0; q < TQ; ++q) {
        float ss = wreds[q][0];
#pragma unroll
        for (int w = 1; w < 8; ++w) ss += wreds[q][w];
        inv[q] = 1.0f / ss;
    }

    // ---- write normalized attn (wave-coalesced 256B stores) ----
#pragma unroll
    for (int q = 0; q < TQ; ++q) {
        const size_t base = (((size_t)(b * NUM_HEADS + h)) * SEQ + (q0 + q)) * (size_t)SEQ;
#pragma unroll
        for (int i = 0; i < 4; ++i)
            attn[base + tid + i * 512] = loc[q][i] * inv[q];
    }

    // ---- fused PV: thread owns 8q x 4d over a 64-wide k slice ----
    const int d4 = (tid & 15) * 4;      // 0..60
    const int kg = tid >> 4;            // 0..31 k-group, 64 k each
    float acc[TQ][4];
#pragma unroll
    for (int q = 0; q < TQ; ++q)
#pragma unroll
        for (int j = 0; j < 4; ++j) acc[q][j] = 0.f;

    const float* Vb = Vp + ((size_t)b * SEQ) * D_MODEL + h * 64 + d4;
#pragma unroll 4
    for (int ks = 0; ks < 64; ks += 4) {
        const int k = kg * 64 + ks;
        const float4 vv0 = *(const float4*)(Vb + (size_t)(k + 0) * D_MODEL);
        const float4 vv1 = *(const float4*)(Vb + (size_t)(k + 1) * D_MODEL);
        const float4 vv2 = *(const float4*)(Vb + (size_t)(k + 2) * D_MODEL);
        const float4 vv3 = *(const float4*)(Vb + (size_t)(k + 3) * D_MODEL);
#pragma unroll
        for (int q = 0; q < TQ; ++q) {
            const float4 p = *(const float4*)&sc[q][k];
            acc[q][0] += p.x * vv0.x + p.y * vv1.x + p.z * vv2.x + p.w * vv3.x;
            acc[q][1] += p.x * vv0.y + p.y * vv1.y + p.z * vv2.y + p.w * vv3.y;
            acc[q][2] += p.x * vv0.z + p.y * vv1.z + p.z * vv2.z + p.w * vv3.z;
            acc[q][3] += p.x * vv0.w + p.y * vv1.w + p.z * vv2.w + p.w * vv3.w;
        }
    }

    // ---- reduce the 32 k-groups through LDS (reuse sc: exactly 16384 floats) ----
    __syncthreads();   // all sc reads done
    float* red = &sc[0][0];             // red[kg][q][d] = [32][8][64]
#pragma unroll
    for (int q = 0; q < TQ; ++q) {
        float4 o;
        o.x = acc[q][0]; o.y = acc[q][1]; o.z = acc[q][2]; o.w = acc[q][3];
        *(float4*)&red[((size_t)kg * TQ + q) * 64 + d4] = o;
    }
    __syncthreads();
    {
        const int q = tid >> 6, d = tid & 63;
        float s = 0.f;
#pragma unroll
        for (int g = 0; g < 32; ++g) s += red[((size_t)g * TQ + q) * 64 + d];
        ctx[((size_t)(b * SEQ + q0 + q)) * D_MODEL + h * 64 + d] = s * inv[q];
    }
}

// ---------------------------------------------------------------------------
extern "C" void kernel_launch(void* const* d_in, const int* in_sizes, int n_in,
                              void* d_out, int out_size, void* d_ws, size_t ws_size,
                              hipStream_t stream) {
    const float* query = (const float*)d_in[0];
    const float* key   = (const float*)d_in[1];
    const float* value = (const float*)d_in[2];
    const float* Wq = (const float*)d_in[3];
    const float* bq = (const float*)d_in[4];
    const float* Wk = (const float*)d_in[5];
    const float* bk = (const float*)d_in[6];
    const float* Wv = (const float*)d_in[7];
    const float* bv = (const float*)d_in[8];
    const float* Wo = (const float*)d_in[9];
    const float* bo = (const float*)d_in[10];

    float* out  = (float*)d_out;                               // [B,S,D]
    float* attn = out + (size_t)BATCH * SEQ * D_MODEL;         // [B,H,S,S]

    const size_t MAT = (size_t)BATCH * SEQ * D_MODEL;          // 4096*1024
    float* ws  = (float*)d_ws;
    float* Qp  = ws;
    float* Kp  = Qp + MAT;
    float* Vp  = Kp + MAT;
    float* ctx = Vp + MAT;

    const int M = BATCH * SEQ;                                 // 4096
    dim3 gblk(256), ggrid(D_MODEL / 64, M / 64);

    gemm_bias_kernel<<<ggrid, gblk, 0, stream>>>(query, Wq, bq, Qp);
    gemm_bias_kernel<<<ggrid, gblk, 0, stream>>>(key,   Wk, bk, Kp);
    gemm_bias_kernel<<<ggrid, gblk, 0, stream>>>(value, Wv, bv, Vp);

    dim3 agrid(SEQ / TQ, NUM_HEADS, BATCH);
    attn_kernel<<<agrid, 512, 0, stream>>>(Qp, Kp, Vp, attn, ctx);

    gemm_bias_kernel<<<ggrid, gblk, 0, stream>>>(ctx, Wo, bo, out);
}